// Round 8
// baseline (206.951 us; speedup 1.0000x reference)
//
#include <hip/hip_runtime.h>

// RejectionSampler: B=128 requests, S=8 draft tokens each, V=32000 vocab.
// Inputs (setup_inputs order):
//  0 target_logits [T*V] f32, 1 draft_probs [T*V] f32, 2 draft_token_ids [T] i32,
//  3 bonus_token_ids [B] i32, 4 temperature [B] f32, 5 uniform_probs [T] f32,
//  6 q [B*V] f32, 7 cu_num_draft_tokens [B] i32 (unused: uniform raggedness)
// Output: output_token_ids [B, S+1] int32.
//
// Division-free, max-free math (positive rescalings preserve decisions):
//   e = exp2(l * log2e/temp)   (|l*c| small for this data: no overflow)
//   accept:  e_t >= u*d_t*D,  D = sum e  (fixed reduction order, stored once)
//   argmax((e/D - d)/q) == argmax(e*rcp(q) - D*(d*rcp(q)))
//
// Output consumes recovered[t] only at the FIRST rejected position of each
// request (<=128 of 1024 tokens). Two kernels, serial tails fused via the
// last-arriver pattern (AGENT-scope release/acquire atomics, safe across
// non-coherent per-XCD L2s):
//   K1: per-token softmax denom (one block/token); last of a request's 8
//       blocks runs the accept scan + finalize + worklist entry inline.
//   K3: chunked residual argmax for worklist tokens only; last of the 8
//       chunk-blocks combines candidates and patches the recovered slot.
// Counters zeroed per call by a 1KB hipMemsetAsync (graph memset node).

constexpr int PLACEHOLDER = -1;
constexpr int B = 128;
constexpr int S = 8;
constexpr int V = 32000;
constexpr int T = B * S;
constexpr int NV4 = V / 4;            // 8000 float4 per row
constexpr int CHUNKS = 8;
constexpr int CV4 = NV4 / CHUNKS;     // 1000 float4 per chunk

extern "C" __device__ float __builtin_amdgcn_exp2f(float);
extern "C" __device__ float __builtin_amdgcn_rcpf(float);

// -------- K1: per-token denom + fused accept/finalize (last-arriver) --------
__global__ __launch_bounds__(512)
void k1_sum(const float* __restrict__ logits,
            const float* __restrict__ dprobs,
            const int*   __restrict__ draft_ids,
            const int*   __restrict__ bonus_ids,
            const float* __restrict__ temperature,
            const float* __restrict__ uniform_probs,
            float* __restrict__ w_D,      // [T]
            int*   __restrict__ c1,       // [B] zeroed per call
            int*   __restrict__ w_need,   // [B]
            int*   __restrict__ w_pos,    // [B]
            int*   __restrict__ out)      // [B*(S+1)]
{
    const int t   = blockIdx.x;                  // one block per token
    const int req = t >> 3;
    const int tid = threadIdx.x, lane = tid & 63, wid = tid >> 6;  // 8 waves
    __shared__ float s_red[8];

    const float c = 1.4426950408889634f / temperature[req];
    const float4* lrow = (const float4*)(logits + (size_t)t * V);

    float lsum = 0.f;
    #pragma unroll 4
    for (int j = 0; j < 16; ++j) {
        const int i4 = j * 512 + tid;
        if (i4 < NV4) {
            const float4 v = lrow[i4];
            lsum += (__builtin_amdgcn_exp2f(v.x * c) +
                     __builtin_amdgcn_exp2f(v.y * c)) +
                    (__builtin_amdgcn_exp2f(v.z * c) +
                     __builtin_amdgcn_exp2f(v.w * c));
        }
    }
    #pragma unroll
    for (int off = 32; off >= 1; off >>= 1)
        lsum += __shfl_xor(lsum, off, 64);
    if (lane == 0) s_red[wid] = lsum;
    __syncthreads();

    if (tid == 0) {
        const float D = ((s_red[0] + s_red[1]) + (s_red[2] + s_red[3])) +
                        ((s_red[4] + s_red[5]) + (s_red[6] + s_red[7]));
        __hip_atomic_store(&w_D[t], D, __ATOMIC_RELEASE,
                           __HIP_MEMORY_SCOPE_AGENT);
        const int old = __hip_atomic_fetch_add(&c1[req], 1, __ATOMIC_ACQ_REL,
                                               __HIP_MEMORY_SCOPE_AGENT);
        if (old == S - 1) {
            // last arriver: per-request accept scan (bit-identical to r6 K2)
            const int b = req;
            float l_d[S], d_d[S], Dv[S], u[S];
            int dt[S];
            #pragma unroll
            for (int p = 0; p < S; ++p) {
                const int tt = b * S + p;
                dt[p]  = draft_ids[tt];
                l_d[p] = logits[(size_t)tt * V + dt[p]];
                d_d[p] = dprobs[(size_t)tt * V + dt[p]];
                u[p]   = uniform_probs[tt];
                Dv[p]  = __hip_atomic_load(&w_D[tt], __ATOMIC_ACQUIRE,
                                           __HIP_MEMORY_SCOPE_AGENT);
            }
            bool alive = true;
            int need_t = -1, need_p = -1;
            #pragma unroll
            for (int p = 0; p < S; ++p) {
                const float e_d = __builtin_amdgcn_exp2f(l_d[p] * c);
                const bool  acc = (d_d[p] > 0.f) &&
                                  (e_d >= u[p] * d_d[p] * Dv[p]);
                int tok = PLACEHOLDER;
                if (alive) {
                    if (acc) tok = dt[p];
                    else if (need_t < 0) { need_t = b * S + p; need_p = p; }
                }
                out[b * (S + 1) + p] = tok;
                alive = alive && acc;
            }
            out[b * (S + 1) + S] = alive ? bonus_ids[b] : PLACEHOLDER;
            w_need[b] = need_t;
            w_pos[b]  = need_p;
        }
    }
}

// -------- K3: chunked residual argmax + fused combine/patch (last-arriver) --
__global__ __launch_bounds__(256)
void k3_arg(const float* __restrict__ logits,
            const float* __restrict__ dprobs,
            const float* __restrict__ q,
            const float* __restrict__ temperature,
            const int*   __restrict__ w_need,
            const int*   __restrict__ w_pos,
            const float* __restrict__ w_D,
            float* __restrict__ w_bv,     // [B*CHUNKS]
            int*   __restrict__ w_bi,     // [B*CHUNKS]
            int*   __restrict__ c2,       // [B] zeroed per call
            int*   __restrict__ out)
{
    const int bid = blockIdx.x;
    const int b = bid >> 3, k = bid & 7;
    const int t = w_need[b];                     // block-uniform
    if (t < 0) return;
    const int tid = threadIdx.x, lane = tid & 63, wid = tid >> 6;
    __shared__ float s_bval[4];
    __shared__ int   s_bidx[4];

    const float c = 1.4426950408889634f / temperature[b];
    const float D = w_D[t];

    const float4* lrow = (const float4*)(logits + (size_t)t * V) + k * CV4;
    const float4* drow = (const float4*)(dprobs + (size_t)t * V) + k * CV4;
    const float4* qrow = (const float4*)(q      + (size_t)b * V) + k * CV4;

    float4 lv[4], dv[4], qv[4];
    #pragma unroll
    for (int j = 0; j < 4; ++j) {
        const int i4 = j * 256 + tid;
        if (i4 < CV4) lv[j] = lrow[i4];
    }
    #pragma unroll
    for (int j = 0; j < 4; ++j) {
        const int i4 = j * 256 + tid;
        if (i4 < CV4) dv[j] = drow[i4];
    }
    #pragma unroll
    for (int j = 0; j < 4; ++j) {
        const int i4 = j * 256 + tid;
        if (i4 < CV4) qv[j] = qrow[i4];
    }

    float bestv = -__builtin_inff();
    int   besti = 0x7fffffff;

#define RS_COMP(LC, DC, QC, GIDX)                                          \
    {                                                                      \
        const float e  = __builtin_amdgcn_exp2f((LC) * c);                 \
        const float rq = __builtin_amdgcn_rcpf(QC);                        \
        const float r  = fmaf(-((DC) * rq), D, e * rq);                    \
        if (r > bestv) { bestv = r; besti = (GIDX); }                      \
    }

    #pragma unroll
    for (int j = 0; j < 4; ++j) {
        const int i4 = j * 256 + tid;
        if (i4 < CV4) {
            const int base = (k * CV4 + i4) * 4;   // global vocab index
            RS_COMP(lv[j].x, dv[j].x, qv[j].x, base + 0)
            RS_COMP(lv[j].y, dv[j].y, qv[j].y, base + 1)
            RS_COMP(lv[j].z, dv[j].z, qv[j].z, base + 2)
            RS_COMP(lv[j].w, dv[j].w, qv[j].w, base + 3)
        }
    }
#undef RS_COMP

    #pragma unroll
    for (int off = 32; off >= 1; off >>= 1) {
        const float ov = __shfl_xor(bestv, off, 64);
        const int   oi = __shfl_xor(besti, off, 64);
        if (ov > bestv || (ov == bestv && oi < besti)) { bestv = ov; besti = oi; }
    }
    if (lane == 0) { s_bval[wid] = bestv; s_bidx[wid] = besti; }
    __syncthreads();

    if (tid == 0) {
        float bv = s_bval[0]; int bi = s_bidx[0];
        #pragma unroll
        for (int w = 1; w < 4; ++w) {
            const float ov = s_bval[w]; const int oi = s_bidx[w];
            if (ov > bv || (ov == bv && oi < bi)) { bv = ov; bi = oi; }
        }
        __hip_atomic_store(&w_bv[bid], bv, __ATOMIC_RELEASE,
                           __HIP_MEMORY_SCOPE_AGENT);
        __hip_atomic_store(&w_bi[bid], bi, __ATOMIC_RELEASE,
                           __HIP_MEMORY_SCOPE_AGENT);
        const int old = __hip_atomic_fetch_add(&c2[b], 1, __ATOMIC_ACQ_REL,
                                               __HIP_MEMORY_SCOPE_AGENT);
        if (old == CHUNKS - 1) {
            // ascending k: chunk k's indices all precede chunk k+1's; strict >
            // with min-index tiebreak == jnp.argmax first-index rule
            float cbv = -__builtin_inff(); int cbi = 0x7fffffff;
            #pragma unroll
            for (int kk = 0; kk < CHUNKS; ++kk) {
                const float ov = __hip_atomic_load(&w_bv[(b << 3) + kk],
                                                   __ATOMIC_ACQUIRE,
                                                   __HIP_MEMORY_SCOPE_AGENT);
                const int   oi = __hip_atomic_load(&w_bi[(b << 3) + kk],
                                                   __ATOMIC_ACQUIRE,
                                                   __HIP_MEMORY_SCOPE_AGENT);
                if (ov > cbv || (ov == cbv && oi < cbi)) { cbv = ov; cbi = oi; }
            }
            out[b * (S + 1) + w_pos[b]] = cbi;
        }
    }
}

extern "C" void kernel_launch(void* const* d_in, const int* in_sizes, int n_in,
                              void* d_out, int out_size, void* d_ws, size_t ws_size,
                              hipStream_t stream) {
    const float* logits      = (const float*)d_in[0];
    const float* dprobs      = (const float*)d_in[1];
    const int*   draft_ids   = (const int*)d_in[2];
    const int*   bonus_ids   = (const int*)d_in[3];
    const float* temperature = (const float*)d_in[4];
    const float* uniform     = (const float*)d_in[5];
    const float* q           = (const float*)d_in[6];
    // d_in[7] cu_num_draft_tokens unused (uniform S per request)

    int* out = (int*)d_out;
    float* w_D    = (float*)d_ws;                 // [T]
    int*   w_need = (int*)(w_D + T);              // [B]
    int*   w_pos  = w_need + B;                   // [B]
    float* w_bv   = (float*)(w_pos + B);          // [B*CHUNKS]
    int*   w_bi   = (int*)(w_bv + B * CHUNKS);    // [B*CHUNKS]
    int*   c1     = w_bi + B * CHUNKS;            // [B]
    int*   c2     = c1 + B;                       // [B]

    // zero the two counter arrays (graph-capturable memset node, 1 KB)
    hipMemsetAsync(c1, 0, 2 * B * sizeof(int), stream);

    k1_sum<<<T, 512, 0, stream>>>(logits, dprobs, draft_ids, bonus_ids,
                                  temperature, uniform,
                                  w_D, c1, w_need, w_pos, out);
    k3_arg<<<B * CHUNKS, 256, 0, stream>>>(logits, dprobs, q, temperature,
                                           w_need, w_pos, w_D,
                                           w_bv, w_bi, c2, out);
}

// Round 9
// 35.760 us; speedup vs baseline: 5.7871x; 5.7871x over previous
//
#include <hip/hip_runtime.h>

// RejectionSampler: B=128 requests, S=8 draft tokens each, V=32000 vocab.
// Inputs (setup_inputs order):
//  0 target_logits [T*V] f32, 1 draft_probs [T*V] f32, 2 draft_token_ids [T] i32,
//  3 bonus_token_ids [B] i32, 4 temperature [B] f32, 5 uniform_probs [T] f32,
//  6 q [B*V] f32, 7 cu_num_draft_tokens [B] i32 (unused: uniform raggedness)
// Output: output_token_ids [B, S+1] int32.
//
// Division-free, max-free math (positive rescalings preserve decisions):
//   e = exp2(l * log2e/temp)   (|l*c| small for this data: no overflow)
//   accept:  e_t >= u*d_t*D,  D = sum e  (fixed reduction order, stored once)
//   argmax((e/D - d)/q) == argmax(e*rcp(q) - D*(d*rcp(q)))
//
// Output consumes recovered[t] only at the FIRST rejected position of each
// request (<=128 of 1024 tokens). TWO dispatches, no cross-block comms
// (kernel boundary provides cross-XCD visibility; round-8's agent-scope
// atomic fences caused an L2-flush storm — never again O(grid) fences):
//   K1: per-token softmax denom D (one block/token, contiguous 128 KB row).
//   K2: one block per request: wave0 does the accept scan via ballot and
//       writes the output row; if a rejection exists, all 16 waves stream
//       that token's l/d/q rows, block-argmax, lane0 patches the slot.

constexpr int PLACEHOLDER = -1;
constexpr int B = 128;
constexpr int S = 8;
constexpr int V = 32000;
constexpr int T = B * S;
constexpr int NV4 = V / 4;            // 8000 float4 per row

extern "C" __device__ float __builtin_amdgcn_exp2f(float);
extern "C" __device__ float __builtin_amdgcn_rcpf(float);

// ---------------- K1: per-token softmax denominator ----------------
__global__ __launch_bounds__(512)
void k1_sum(const float* __restrict__ logits,
            const float* __restrict__ temperature,
            float* __restrict__ w_D)
{
    const int t   = blockIdx.x;
    const int tid = threadIdx.x, lane = tid & 63, wid = tid >> 6;  // 8 waves
    __shared__ float s_red[8];

    const float c = 1.4426950408889634f / temperature[t >> 3];
    const float4* lrow = (const float4*)(logits + (size_t)t * V);

    float lsum = 0.f;
    #pragma unroll 4
    for (int j = 0; j < 16; ++j) {
        const int i4 = j * 512 + tid;
        if (i4 < NV4) {
            const float4 v = lrow[i4];
            lsum += (__builtin_amdgcn_exp2f(v.x * c) +
                     __builtin_amdgcn_exp2f(v.y * c)) +
                    (__builtin_amdgcn_exp2f(v.z * c) +
                     __builtin_amdgcn_exp2f(v.w * c));
        }
    }
    #pragma unroll
    for (int off = 32; off >= 1; off >>= 1)
        lsum += __shfl_xor(lsum, off, 64);
    if (lane == 0) s_red[wid] = lsum;
    __syncthreads();
    if (wid == 0) {
        float v = (lane < 8) ? s_red[lane] : 0.f;
        #pragma unroll
        for (int off = 4; off >= 1; off >>= 1)
            v += __shfl_xor(v, off, 64);
        if (lane == 0) w_D[t] = v;
    }
}

// ------ K2: per-request accept scan + worklist argmax + finalize ------
__global__ __launch_bounds__(1024, 2)
void k2_fin(const float* __restrict__ logits,
            const float* __restrict__ dprobs,
            const float* __restrict__ q,
            const int*   __restrict__ draft_ids,
            const int*   __restrict__ bonus_ids,
            const float* __restrict__ temperature,
            const float* __restrict__ uniform_probs,
            const float* __restrict__ w_D,
            int* __restrict__ out)
{
    const int b   = blockIdx.x;                  // one block per request
    const int tid = threadIdx.x, lane = tid & 63, wid = tid >> 6; // 16 waves
    __shared__ float s_val[16];
    __shared__ int   s_idx[16];
    __shared__ int   s_needp;

    const float c = 1.4426950408889634f / temperature[b];

    // ---- accept scan on wave 0: lanes 0..7 gather their position ----
    if (wid == 0) {
        bool acc = false;
        int  dt  = 0;
        if (lane < S) {
            const int t = b * S + lane;
            dt = draft_ids[t];
            const float l_d = logits[(size_t)t * V + dt];
            const float d_d = dprobs[(size_t)t * V + dt];
            const float u   = uniform_probs[t];
            const float Dv  = w_D[t];
            const float e_d = __builtin_amdgcn_exp2f(l_d * c);
            acc = (d_d > 0.f) && (e_d >= u * d_d * Dv);
        }
        const unsigned long long mask = __ballot(lane < S && acc);
        const unsigned long long rej  = (~mask) & 0xFFull;
        const int need_p = rej ? (int)__builtin_ctzll(rej) : S;
        if (lane < S)
            out[b * (S + 1) + lane] = (lane < need_p) ? dt : PLACEHOLDER;
        if (lane == 0) {
            out[b * (S + 1) + S] = (need_p == S) ? bonus_ids[b] : PLACEHOLDER;
            s_needp = need_p;
        }
    }
    __syncthreads();
    const int need_p = s_needp;                  // block-uniform
    if (need_p >= S) return;                     // all accepted: done

    // ---- residual argmax for the single needed token ----
    const int   t = b * S + need_p;
    const float D = w_D[t];
    const float4* lrow = (const float4*)(logits + (size_t)t * V);
    const float4* drow = (const float4*)(dprobs + (size_t)t * V);
    const float4* qrow = (const float4*)(q      + (size_t)b * V);

    float bestv = -__builtin_inff();
    int   besti = 0x7fffffff;

#define RS_COMP(LC, DC, QC, GIDX)                                          \
    {                                                                      \
        const float e  = __builtin_amdgcn_exp2f((LC) * c);                 \
        const float rq = __builtin_amdgcn_rcpf(QC);                        \
        const float r  = fmaf(-((DC) * rq), D, e * rq);                    \
        if (r > bestv) { bestv = r; besti = (GIDX); }                      \
    }

    #pragma unroll 2
    for (int j = 0; j < 8; ++j) {
        const int i4 = j * 1024 + tid;
        if (i4 < NV4) {
            const float4 lv = lrow[i4];
            const float4 dv = drow[i4];
            const float4 qv = qrow[i4];
            const int base  = i4 * 4;
            RS_COMP(lv.x, dv.x, qv.x, base + 0)
            RS_COMP(lv.y, dv.y, qv.y, base + 1)
            RS_COMP(lv.z, dv.z, qv.z, base + 2)
            RS_COMP(lv.w, dv.w, qv.w, base + 3)
        }
    }
#undef RS_COMP

    // wave butterfly then wave-0 cross-wave reduce (min-index ties)
    #pragma unroll
    for (int off = 32; off >= 1; off >>= 1) {
        const float ov = __shfl_xor(bestv, off, 64);
        const int   oi = __shfl_xor(besti, off, 64);
        if (ov > bestv || (ov == bestv && oi < besti)) { bestv = ov; besti = oi; }
    }
    if (lane == 0) { s_val[wid] = bestv; s_idx[wid] = besti; }
    __syncthreads();
    if (wid == 0) {
        float bv = (lane < 16) ? s_val[lane] : -__builtin_inff();
        int   bi = (lane < 16) ? s_idx[lane] : 0x7fffffff;
        #pragma unroll
        for (int off = 8; off >= 1; off >>= 1) {
            const float ov = __shfl_xor(bv, off, 64);
            const int   oi = __shfl_xor(bi, off, 64);
            if (ov > bv || (ov == bv && oi < bi)) { bv = ov; bi = oi; }
        }
        if (lane == 0)
            out[b * (S + 1) + need_p] = bi;
    }
}

extern "C" void kernel_launch(void* const* d_in, const int* in_sizes, int n_in,
                              void* d_out, int out_size, void* d_ws, size_t ws_size,
                              hipStream_t stream) {
    const float* logits      = (const float*)d_in[0];
    const float* dprobs      = (const float*)d_in[1];
    const int*   draft_ids   = (const int*)d_in[2];
    const int*   bonus_ids   = (const int*)d_in[3];
    const float* temperature = (const float*)d_in[4];
    const float* uniform     = (const float*)d_in[5];
    const float* q           = (const float*)d_in[6];
    // d_in[7] cu_num_draft_tokens unused (uniform S per request)

    int* out = (int*)d_out;
    float* w_D = (float*)d_ws;                    // [T]

    k1_sum<<<T, 512, 0, stream>>>(logits, temperature, w_D);
    k2_fin<<<B, 1024, 0, stream>>>(logits, dprobs, q, draft_ids, bonus_ids,
                                   temperature, uniform, w_D, out);
}